// Round 5
// baseline (6223.399 us; speedup 1.0000x reference)
//
#include <hip/hip_runtime.h>
#include <hip/hip_bf16.h>

#define NFEAT 512
#define NHID  256
#define NOUT  64
#define NUM_LAYERS 8

// ---------------------------------------------------------------------------
// Graph preprocessing: degree histogram, dinv, exclusive scan -> rowptr, CSR
// ---------------------------------------------------------------------------

__global__ void hist_kernel(const int* __restrict__ ei, int E, int* __restrict__ cnt) {
    int e = blockIdx.x * blockDim.x + threadIdx.x;
    if (e < E) atomicAdd(&cnt[ei[e]], 1);
}

__global__ void dinv_kernel(const int* __restrict__ cnt, float* __restrict__ dinv, int n) {
    int i = blockIdx.x * blockDim.x + threadIdx.x;
    if (i < n) dinv[i] = rsqrtf((float)cnt[i] + 1.0f);  // +1 = self loop; deg>=1 always
}

// chunk = 1024 elements per 256-thread block, 4 per thread
__global__ __launch_bounds__(256)
void scan_blocks(const int* __restrict__ cnt, int* __restrict__ out,
                 int* __restrict__ partials, int n) {
    __shared__ int sdata[256];
    int tid  = threadIdx.x;
    int base = blockIdx.x * 1024 + tid * 4;
    int v[4];
    int s = 0;
    #pragma unroll
    for (int j = 0; j < 4; ++j) {
        int x = (base + j < n) ? cnt[base + j] : 0;
        s += x;
        v[j] = s;                       // inclusive within thread
    }
    sdata[tid] = s;
    __syncthreads();
    #pragma unroll
    for (int off = 1; off < 256; off <<= 1) {
        int t = (tid >= off) ? sdata[tid - off] : 0;
        __syncthreads();
        sdata[tid] += t;
        __syncthreads();
    }
    int excl = sdata[tid] - s;          // exclusive across threads in block
    #pragma unroll
    for (int j = 0; j < 4; ++j)
        if (base + j < n) out[base + j] = excl + v[j];   // out = rowptr+1 (inclusive scan)
    if (tid == 255) partials[blockIdx.x] = sdata[255];
}

__global__ __launch_bounds__(256)
void scan_partials(int* __restrict__ partials, int nb) {
    __shared__ int sdata[256];
    int tid = threadIdx.x;
    int s = (tid < nb) ? partials[tid] : 0;
    sdata[tid] = s;
    __syncthreads();
    #pragma unroll
    for (int off = 1; off < 256; off <<= 1) {
        int t = (tid >= off) ? sdata[tid - off] : 0;
        __syncthreads();
        sdata[tid] += t;
        __syncthreads();
    }
    if (tid < nb) partials[tid] = sdata[tid] - s;        // exclusive
}

__global__ void scan_add(int* __restrict__ rowptr, const int* __restrict__ partials, int n) {
    int i = blockIdx.x * blockDim.x + threadIdx.x;
    if (i == 0) rowptr[0] = 0;
    if (i < n) rowptr[i + 1] += partials[i >> 10];
}

__global__ void scatter_kernel(const int* __restrict__ ei, int E,
                               const int* __restrict__ rowptr, int* __restrict__ fill,
                               const float* __restrict__ dinv,
                               int* __restrict__ csr_col, float* __restrict__ csr_w) {
    int e = blockIdx.x * blockDim.x + threadIdx.x;
    if (e >= E) return;
    int r = ei[e];
    int c = ei[E + e];
    int pos = rowptr[r] + atomicAdd(&fill[r], 1);
    csr_col[pos] = c;
    csr_w[pos]   = dinv[r] * dinv[c];
}

// ---------------------------------------------------------------------------
// SpMM: one wave (64 lanes) per row, 256 feats = 64 x float4.
// mixed = 0.9 * (D^-1/2 (A+I) D^-1/2 h) + 0.1 * x0   (fused)
// Edge loop unrolled x4: 4 independent 1KB gathers in flight per wave.
// ---------------------------------------------------------------------------

__global__ __launch_bounds__(256)
void spmm_kernel(const int* __restrict__ rowptr, const int* __restrict__ csr_col,
                 const float* __restrict__ csr_w, const float* __restrict__ dinv,
                 const float* __restrict__ h, const float* __restrict__ x0,
                 float* __restrict__ mixed, int n) {
    int row = blockIdx.x * 4 + (threadIdx.x >> 6);
    if (row >= n) return;
    int lane = threadIdx.x & 63;
    const float4* hv = (const float4*)h;
    float dr = dinv[row];

    float4 v = hv[(size_t)row * 64 + lane];              // self loop
    float ws = dr * dr;
    float4 acc;
    acc.x = ws * v.x; acc.y = ws * v.y; acc.z = ws * v.z; acc.w = ws * v.w;

    int beg = rowptr[row], end = rowptr[row + 1];
    int j = beg;
    for (; j + 3 < end; j += 4) {
        int c0 = __builtin_amdgcn_readfirstlane(csr_col[j + 0]);
        int c1 = __builtin_amdgcn_readfirstlane(csr_col[j + 1]);
        int c2 = __builtin_amdgcn_readfirstlane(csr_col[j + 2]);
        int c3 = __builtin_amdgcn_readfirstlane(csr_col[j + 3]);
        float w0 = csr_w[j + 0], w1 = csr_w[j + 1];
        float w2 = csr_w[j + 2], w3 = csr_w[j + 3];
        float4 u0 = hv[(size_t)c0 * 64 + lane];
        float4 u1 = hv[(size_t)c1 * 64 + lane];
        float4 u2 = hv[(size_t)c2 * 64 + lane];
        float4 u3 = hv[(size_t)c3 * 64 + lane];
        acc.x += w0 * u0.x; acc.y += w0 * u0.y; acc.z += w0 * u0.z; acc.w += w0 * u0.w;
        acc.x += w1 * u1.x; acc.y += w1 * u1.y; acc.z += w1 * u1.z; acc.w += w1 * u1.w;
        acc.x += w2 * u2.x; acc.y += w2 * u2.y; acc.z += w2 * u2.z; acc.w += w2 * u2.w;
        acc.x += w3 * u3.x; acc.y += w3 * u3.y; acc.z += w3 * u3.z; acc.w += w3 * u3.w;
    }
    for (; j < end; ++j) {
        int   c  = __builtin_amdgcn_readfirstlane(csr_col[j]);
        float wc = csr_w[j];
        float4 u = hv[(size_t)c * 64 + lane];
        acc.x += wc * u.x; acc.y += wc * u.y; acc.z += wc * u.z; acc.w += wc * u.w;
    }
    float4 xv = ((const float4*)x0)[(size_t)row * 64 + lane];
    float4 o;
    o.x = 0.9f * acc.x + 0.1f * xv.x;
    o.y = 0.9f * acc.y + 0.1f * xv.y;
    o.z = 0.9f * acc.z + 0.1f * xv.z;
    o.w = 0.9f * acc.w + 0.1f * xv.w;
    ((float4*)mixed)[(size_t)row * 64 + lane] = o;
}

// ---------------------------------------------------------------------------
// fp32 GEMM: out = act(A @ W + bias? + addend?), optional out2 mirror.
// BM=BN=128, BK=16, 256 threads, 8x8 microtile. In-place (out==addend) safe.
// ---------------------------------------------------------------------------

template <bool RELU>
__global__ __launch_bounds__(256)
void gemm_kernel(const float* __restrict__ A, const float* __restrict__ W,
                 const float* __restrict__ bias, const float* __restrict__ addend,
                 float* __restrict__ out, float* __restrict__ out2,
                 int M, int K, int Nn) {
    __shared__ float As[16][128];
    __shared__ float Bs[16][128];
    int tid = threadIdx.x;
    int bm = blockIdx.x * 128;
    int bn = blockIdx.y * 128;

    int arow = tid >> 1;
    int acol = (tid & 1) * 8;
    int brow = tid >> 4;
    int bcol = (tid & 15) * 8;
    int x = tid & 15, y = tid >> 4;

    float acc[8][8] = {};

    for (int k0 = 0; k0 < K; k0 += 16) {
        // A tile: rows bm..bm+127, cols k0..k0+15
        {
            int gr = bm + arow;
            float4 v0 = {0,0,0,0}, v1 = {0,0,0,0};
            if (gr < M) {
                const float* p = A + (size_t)gr * K + k0 + acol;
                v0 = *(const float4*)p;
                v1 = *(const float4*)(p + 4);
            }
            As[acol + 0][arow] = v0.x; As[acol + 1][arow] = v0.y;
            As[acol + 2][arow] = v0.z; As[acol + 3][arow] = v0.w;
            As[acol + 4][arow] = v1.x; As[acol + 5][arow] = v1.y;
            As[acol + 6][arow] = v1.z; As[acol + 7][arow] = v1.w;
        }
        // B tile: rows k0..k0+15 of W, cols bn..bn+127
        {
            float4 v0 = {0,0,0,0}, v1 = {0,0,0,0};
            if (bn + bcol < Nn) {                      // Nn % 8 == 0
                const float* p = W + (size_t)(k0 + brow) * Nn + bn + bcol;
                v0 = *(const float4*)p;
                v1 = *(const float4*)(p + 4);
            }
            *(float4*)&Bs[brow][bcol]     = v0;
            *(float4*)&Bs[brow][bcol + 4] = v1;
        }
        __syncthreads();
        #pragma unroll
        for (int k = 0; k < 16; ++k) {
            float a[8], b[8];
            *(float4*)&a[0] = *(const float4*)&As[k][y * 8];
            *(float4*)&a[4] = *(const float4*)&As[k][y * 8 + 4];
            *(float4*)&b[0] = *(const float4*)&Bs[k][x * 8];
            *(float4*)&b[4] = *(const float4*)&Bs[k][x * 8 + 4];
            #pragma unroll
            for (int i = 0; i < 8; ++i)
                #pragma unroll
                for (int j = 0; j < 8; ++j)
                    acc[i][j] = fmaf(a[i], b[j], acc[i][j]);
        }
        __syncthreads();
    }

    #pragma unroll
    for (int i = 0; i < 8; ++i) {
        int gr = bm + y * 8 + i;
        if (gr >= M) continue;
        size_t ro = (size_t)gr * Nn;
        #pragma unroll
        for (int jj = 0; jj < 8; jj += 4) {
            int gc = bn + x * 8 + jj;
            if (gc >= Nn) continue;                    // Nn % 8 == 0
            float4 v;
            v.x = acc[i][jj + 0]; v.y = acc[i][jj + 1];
            v.z = acc[i][jj + 2]; v.w = acc[i][jj + 3];
            if (bias) {
                float4 bv = *(const float4*)(bias + gc);
                v.x += bv.x; v.y += bv.y; v.z += bv.z; v.w += bv.w;
            }
            if (addend) {
                float4 ad = *(const float4*)(addend + ro + gc);
                v.x += ad.x; v.y += ad.y; v.z += ad.z; v.w += ad.w;
            }
            if (RELU) {
                v.x = fmaxf(v.x, 0.f); v.y = fmaxf(v.y, 0.f);
                v.z = fmaxf(v.z, 0.f); v.w = fmaxf(v.w, 0.f);
            }
            *(float4*)(out + ro + gc) = v;
            if (out2) *(float4*)(out2 + ro + gc) = v;
        }
    }
}

// ---------------------------------------------------------------------------

extern "C" void kernel_launch(void* const* d_in, const int* in_sizes, int n_in,
                              void* d_out, int out_size, void* d_ws, size_t ws_size,
                              hipStream_t stream) {
    const float* x      = (const float*)d_in[0];
    const int*   ei     = (const int*)d_in[1];
    const float* W1     = (const float*)d_in[2];
    const float* b1     = (const float*)d_in[3];
    const float* W2     = (const float*)d_in[4];
    const float* b2     = (const float*)d_in[5];
    const float* conv_w = (const float*)d_in[6];

    const int M = in_sizes[0] / NFEAT;   // 100000
    const int E = in_sizes[1] / 2;       // 3200000

    char* ws = (char*)d_ws;
    size_t off = 0;
    auto alloc = [&](size_t bytes) -> void* {
        off = (off + 255) & ~(size_t)255;
        void* p = ws + off;
        off += bytes;
        return p;
    };
    int*   cnt      = (int*)  alloc((size_t)M * 4);
    int*   fill     = (int*)  alloc((size_t)M * 4);
    int*   rowptr   = (int*)  alloc((size_t)(M + 1) * 4);
    int*   partials = (int*)  alloc(256 * 4);
    float* dinv     = (float*)alloc((size_t)M * 4);
    int*   csr      = (int*)  alloc((size_t)E * 4);
    float* csr_w    = (float*)alloc((size_t)E * 4);
    float* h        = (float*)alloc((size_t)M * NHID * 4);
    float* x0       = (float*)alloc((size_t)M * NHID * 4);
    float* mixed    = (float*)alloc((size_t)M * NHID * 4);

    // Workspace guard: if d_ws is smaller than required (~334 MB), do nothing
    // rather than OOB-write. Output will fail validation cleanly instead of
    // crashing the container — diagnosable next round.
    if (off > ws_size) return;

    hipMemsetAsync(cnt,  0, (size_t)M * 4, stream);
    hipMemsetAsync(fill, 0, (size_t)M * 4, stream);

    hist_kernel<<<(E + 255) / 256, 256, 0, stream>>>(ei, E, cnt);
    dinv_kernel<<<(M + 255) / 256, 256, 0, stream>>>(cnt, dinv, M);

    int nchunks = (M + 1023) / 1024;     // 98 <= 256
    scan_blocks<<<nchunks, 256, 0, stream>>>(cnt, rowptr + 1, partials, M);
    scan_partials<<<1, 256, 0, stream>>>(partials, nchunks);
    scan_add<<<(M + 255) / 256, 256, 0, stream>>>(rowptr, partials, M);
    scatter_kernel<<<(E + 255) / 256, 256, 0, stream>>>(ei, E, rowptr, fill, dinv,
                                                        csr, csr_w);

    dim3 g1((M + 127) / 128, (NHID + 127) / 128);
    gemm_kernel<true><<<g1, 256, 0, stream>>>(x, W1, b1, nullptr, h, x0, M, NFEAT, NHID);

    for (int l = 0; l < NUM_LAYERS; ++l) {
        spmm_kernel<<<(M + 3) / 4, 256, 0, stream>>>(rowptr, csr, csr_w, dinv, h, x0,
                                                     mixed, M);
        gemm_kernel<true><<<g1, 256, 0, stream>>>(mixed, conv_w + (size_t)l * NHID * NHID,
                                                  nullptr, h, h, nullptr, M, NHID, NHID);
    }

    dim3 g2((M + 127) / 128, 1);
    gemm_kernel<true><<<g2, 256, 0, stream>>>(h, W2, b2, nullptr, (float*)d_out, nullptr,
                                              M, NHID, NOUT);
}

// Round 10
// 6069.407 us; speedup vs baseline: 1.0254x; 1.0254x over previous
//
#include <hip/hip_runtime.h>
#include <hip/hip_bf16.h>

#define NFEAT 512
#define NHID  256
#define NOUT  64
#define NUM_LAYERS 8

// ---------------------------------------------------------------------------
// Graph preprocessing: degree histogram, dinv, exclusive scan -> rowptr, CSR
// ---------------------------------------------------------------------------

__global__ void hist_kernel(const int* __restrict__ ei, int E, int* __restrict__ cnt) {
    int e = blockIdx.x * blockDim.x + threadIdx.x;
    if (e < E) atomicAdd(&cnt[ei[e]], 1);
}

__global__ void dinv_kernel(const int* __restrict__ cnt, float* __restrict__ dinv, int n) {
    int i = blockIdx.x * blockDim.x + threadIdx.x;
    if (i < n) dinv[i] = rsqrtf((float)cnt[i] + 1.0f);  // +1 = self loop
}

__global__ __launch_bounds__(256)
void scan_blocks(const int* __restrict__ cnt, int* __restrict__ out,
                 int* __restrict__ partials, int n) {
    __shared__ int sdata[256];
    int tid  = threadIdx.x;
    int base = blockIdx.x * 1024 + tid * 4;
    int v[4];
    int s = 0;
    #pragma unroll
    for (int j = 0; j < 4; ++j) {
        int x = (base + j < n) ? cnt[base + j] : 0;
        s += x;
        v[j] = s;
    }
    sdata[tid] = s;
    __syncthreads();
    #pragma unroll
    for (int off = 1; off < 256; off <<= 1) {
        int t = (tid >= off) ? sdata[tid - off] : 0;
        __syncthreads();
        sdata[tid] += t;
        __syncthreads();
    }
    int excl = sdata[tid] - s;
    #pragma unroll
    for (int j = 0; j < 4; ++j)
        if (base + j < n) out[base + j] = excl + v[j];
    if (tid == 255) partials[blockIdx.x] = sdata[255];
}

__global__ __launch_bounds__(256)
void scan_partials(int* __restrict__ partials, int nb) {
    __shared__ int sdata[256];
    int tid = threadIdx.x;
    int s = (tid < nb) ? partials[tid] : 0;
    sdata[tid] = s;
    __syncthreads();
    #pragma unroll
    for (int off = 1; off < 256; off <<= 1) {
        int t = (tid >= off) ? sdata[tid - off] : 0;
        __syncthreads();
        sdata[tid] += t;
        __syncthreads();
    }
    if (tid < nb) partials[tid] = sdata[tid] - s;
}

__global__ void scan_add(int* __restrict__ rowptr, const int* __restrict__ partials, int n) {
    int i = blockIdx.x * blockDim.x + threadIdx.x;
    if (i == 0) rowptr[0] = 0;
    if (i < n) rowptr[i + 1] += partials[i >> 10];
}

__global__ void scatter_kernel(const int* __restrict__ ei, int E,
                               const int* __restrict__ rowptr, int* __restrict__ fill,
                               const float* __restrict__ dinv,
                               int* __restrict__ csr_col, float* __restrict__ csr_w) {
    int e = blockIdx.x * blockDim.x + threadIdx.x;
    if (e >= E) return;
    int r = ei[e];
    int c = ei[E + e];
    int pos = rowptr[r] + atomicAdd(&fill[r], 1);
    csr_col[pos] = c;
    csr_w[pos]   = dinv[r] * dinv[c];
}

// ---------------------------------------------------------------------------
// SpMM, feature-split: one wave per row, HALF=128 feats = 64 lanes x float2.
// Two sequential passes (f2off = 0, 64) shrink the per-dispatch gather target
// to 51MB (L3-resident). Round-5 counters: full-width fp32 gather thrashed L3
// (FETCH 1.67GB/dispatch = 50% miss of 3.38GB volume, 500us, HBM-fetch-bound).
// Summation order per output element is unchanged -> bit-compatible numerics.
// mixed = 0.9 * (D^-1/2 (A+I) D^-1/2 h) + 0.1 * x0   (fused)
// ---------------------------------------------------------------------------

__global__ __launch_bounds__(256)
void spmm_kernel(const int* __restrict__ rowptr, const int* __restrict__ csr_col,
                 const float* __restrict__ csr_w, const float* __restrict__ dinv,
                 const float* __restrict__ h, const float* __restrict__ x0,
                 float* __restrict__ mixed, int n, int f2off) {
    int row = blockIdx.x * 4 + (threadIdx.x >> 6);
    if (row >= n) return;
    int lane = threadIdx.x & 63;
    const float2* hv = (const float2*)h;         // row stride = 128 float2
    size_t fi = (size_t)row * 128 + f2off + lane;
    float dr = dinv[row];

    float2 v = hv[fi];                           // self loop
    float ws = dr * dr;
    float2 acc;
    acc.x = ws * v.x; acc.y = ws * v.y;

    int beg = rowptr[row], end = rowptr[row + 1];
    int j = beg;
    for (; j + 3 < end; j += 4) {
        int c0 = __builtin_amdgcn_readfirstlane(csr_col[j + 0]);
        int c1 = __builtin_amdgcn_readfirstlane(csr_col[j + 1]);
        int c2 = __builtin_amdgcn_readfirstlane(csr_col[j + 2]);
        int c3 = __builtin_amdgcn_readfirstlane(csr_col[j + 3]);
        float w0 = csr_w[j + 0], w1 = csr_w[j + 1];
        float w2 = csr_w[j + 2], w3 = csr_w[j + 3];
        float2 u0 = hv[(size_t)c0 * 128 + f2off + lane];
        float2 u1 = hv[(size_t)c1 * 128 + f2off + lane];
        float2 u2 = hv[(size_t)c2 * 128 + f2off + lane];
        float2 u3 = hv[(size_t)c3 * 128 + f2off + lane];
        acc.x += w0 * u0.x; acc.y += w0 * u0.y;
        acc.x += w1 * u1.x; acc.y += w1 * u1.y;
        acc.x += w2 * u2.x; acc.y += w2 * u2.y;
        acc.x += w3 * u3.x; acc.y += w3 * u3.y;
    }
    for (; j < end; ++j) {
        int   c  = __builtin_amdgcn_readfirstlane(csr_col[j]);
        float wc = csr_w[j];
        float2 u = hv[(size_t)c * 128 + f2off + lane];
        acc.x += wc * u.x; acc.y += wc * u.y;
    }
    float2 xv = ((const float2*)x0)[fi];
    float2 o;
    o.x = 0.9f * acc.x + 0.1f * xv.x;
    o.y = 0.9f * acc.y + 0.1f * xv.y;
    ((float2*)mixed)[fi] = o;
}

// ---------------------------------------------------------------------------
// fp32 GEMM: out = act(A @ W + bias? + addend?), optional out2 mirror.
// BM=BN=128, BK=16, 256 threads, 8x8 microtile. In-place (out==addend) safe.
// ---------------------------------------------------------------------------

template <bool RELU>
__global__ __launch_bounds__(256)
void gemm_kernel(const float* __restrict__ A, const float* __restrict__ W,
                 const float* __restrict__ bias, const float* __restrict__ addend,
                 float* __restrict__ out, float* __restrict__ out2,
                 int M, int K, int Nn) {
    __shared__ float As[16][128];
    __shared__ float Bs[16][128];
    int tid = threadIdx.x;
    int bm = blockIdx.x * 128;
    int bn = blockIdx.y * 128;

    int arow = tid >> 1;
    int acol = (tid & 1) * 8;
    int brow = tid >> 4;
    int bcol = (tid & 15) * 8;
    int x = tid & 15, y = tid >> 4;

    float acc[8][8] = {};

    for (int k0 = 0; k0 < K; k0 += 16) {
        {
            int gr = bm + arow;
            float4 v0 = {0,0,0,0}, v1 = {0,0,0,0};
            if (gr < M) {
                const float* p = A + (size_t)gr * K + k0 + acol;
                v0 = *(const float4*)p;
                v1 = *(const float4*)(p + 4);
            }
            As[acol + 0][arow] = v0.x; As[acol + 1][arow] = v0.y;
            As[acol + 2][arow] = v0.z; As[acol + 3][arow] = v0.w;
            As[acol + 4][arow] = v1.x; As[acol + 5][arow] = v1.y;
            As[acol + 6][arow] = v1.z; As[acol + 7][arow] = v1.w;
        }
        {
            float4 v0 = {0,0,0,0}, v1 = {0,0,0,0};
            if (bn + bcol < Nn) {                      // Nn % 8 == 0
                const float* p = W + (size_t)(k0 + brow) * Nn + bn + bcol;
                v0 = *(const float4*)p;
                v1 = *(const float4*)(p + 4);
            }
            *(float4*)&Bs[brow][bcol]     = v0;
            *(float4*)&Bs[brow][bcol + 4] = v1;
        }
        __syncthreads();
        #pragma unroll
        for (int k = 0; k < 16; ++k) {
            float a[8], b[8];
            *(float4*)&a[0] = *(const float4*)&As[k][y * 8];
            *(float4*)&a[4] = *(const float4*)&As[k][y * 8 + 4];
            *(float4*)&b[0] = *(const float4*)&Bs[k][x * 8];
            *(float4*)&b[4] = *(const float4*)&Bs[k][x * 8 + 4];
            #pragma unroll
            for (int i = 0; i < 8; ++i)
                #pragma unroll
                for (int j = 0; j < 8; ++j)
                    acc[i][j] = fmaf(a[i], b[j], acc[i][j]);
        }
        __syncthreads();
    }

    #pragma unroll
    for (int i = 0; i < 8; ++i) {
        int gr = bm + y * 8 + i;
        if (gr >= M) continue;
        size_t ro = (size_t)gr * Nn;
        #pragma unroll
        for (int jj = 0; jj < 8; jj += 4) {
            int gc = bn + x * 8 + jj;
            if (gc >= Nn) continue;
            float4 v;
            v.x = acc[i][jj + 0]; v.y = acc[i][jj + 1];
            v.z = acc[i][jj + 2]; v.w = acc[i][jj + 3];
            if (bias) {
                float4 bv = *(const float4*)(bias + gc);
                v.x += bv.x; v.y += bv.y; v.z += bv.z; v.w += bv.w;
            }
            if (addend) {
                float4 ad = *(const float4*)(addend + ro + gc);
                v.x += ad.x; v.y += ad.y; v.z += ad.z; v.w += ad.w;
            }
            if (RELU) {
                v.x = fmaxf(v.x, 0.f); v.y = fmaxf(v.y, 0.f);
                v.z = fmaxf(v.z, 0.f); v.w = fmaxf(v.w, 0.f);
            }
            *(float4*)(out + ro + gc) = v;
            if (out2) *(float4*)(out2 + ro + gc) = v;
        }
    }
}

// ---------------------------------------------------------------------------

extern "C" void kernel_launch(void* const* d_in, const int* in_sizes, int n_in,
                              void* d_out, int out_size, void* d_ws, size_t ws_size,
                              hipStream_t stream) {
    const float* x      = (const float*)d_in[0];
    const int*   ei     = (const int*)d_in[1];
    const float* W1     = (const float*)d_in[2];
    const float* b1     = (const float*)d_in[3];
    const float* W2     = (const float*)d_in[4];
    const float* b2     = (const float*)d_in[5];
    const float* conv_w = (const float*)d_in[6];

    const int M = in_sizes[0] / NFEAT;   // 100000
    const int E = in_sizes[1] / 2;       // 3200000

    char* ws = (char*)d_ws;
    size_t off = 0;
    auto alloc = [&](size_t bytes) -> void* {
        off = (off + 255) & ~(size_t)255;
        void* p = ws + off;
        off += bytes;
        return p;
    };
    int*   cnt      = (int*)  alloc((size_t)M * 4);
    int*   fill     = (int*)  alloc((size_t)M * 4);
    int*   rowptr   = (int*)  alloc((size_t)(M + 1) * 4);
    int*   partials = (int*)  alloc(256 * 4);
    float* dinv     = (float*)alloc((size_t)M * 4);
    int*   csr      = (int*)  alloc((size_t)E * 4);
    float* csr_w    = (float*)alloc((size_t)E * 4);
    float* h        = (float*)alloc((size_t)M * NHID * 4);
    float* x0       = (float*)alloc((size_t)M * NHID * 4);
    float* mixed    = (float*)alloc((size_t)M * NHID * 4);

    // Workspace guard (~334 MB, same footprint that passed round 5).
    if (off > ws_size) return;

    hipMemsetAsync(cnt,  0, (size_t)M * 4, stream);
    hipMemsetAsync(fill, 0, (size_t)M * 4, stream);

    hist_kernel<<<(E + 255) / 256, 256, 0, stream>>>(ei, E, cnt);
    dinv_kernel<<<(M + 255) / 256, 256, 0, stream>>>(cnt, dinv, M);

    int nchunks = (M + 1023) / 1024;     // 98 <= 256
    scan_blocks<<<nchunks, 256, 0, stream>>>(cnt, rowptr + 1, partials, M);
    scan_partials<<<1, 256, 0, stream>>>(partials, nchunks);
    scan_add<<<(M + 255) / 256, 256, 0, stream>>>(rowptr, partials, M);
    scatter_kernel<<<(E + 255) / 256, 256, 0, stream>>>(ei, E, rowptr, fill, dinv,
                                                        csr, csr_w);

    dim3 g1((M + 127) / 128, (NHID + 127) / 128);
    gemm_kernel<true><<<g1, 256, 0, stream>>>(x, W1, b1, nullptr, h, x0, M, NFEAT, NHID);

    int sgrid = (M + 3) / 4;
    for (int l = 0; l < NUM_LAYERS; ++l) {
        // Two sequential half-feature passes keep the gather set L3-resident.
        spmm_kernel<<<sgrid, 256, 0, stream>>>(rowptr, csr, csr_w, dinv, h, x0,
                                               mixed, M, 0);
        spmm_kernel<<<sgrid, 256, 0, stream>>>(rowptr, csr, csr_w, dinv, h, x0,
                                               mixed, M, 64);
        gemm_kernel<true><<<g1, 256, 0, stream>>>(mixed, conv_w + (size_t)l * NHID * NHID,
                                                  nullptr, h, h, nullptr, M, NHID, NHID);
    }

    dim3 g2((M + 127) / 128, 1);
    gemm_kernel<true><<<g2, 256, 0, stream>>>(h, W2, b2, nullptr, (float*)d_out, nullptr,
                                              M, NHID, NOUT);
}